// Round 6
// baseline (56.709 us; speedup 1.0000x reference)
//
#include <hip/hip_runtime.h>
#include <math.h>

#define BB 32
#define SS 2048
#define DD 1024

// ws layout (floats), nch = chunks per b (64 preferred, 32 fallback):
//   energy : BB*SS
//   partial: BB*nch*DD
//   ml     : BB*nch*2

// K1: fused energy + online-softmax PV.
// Block = (b, chunk). Thread owns one float4 slice of D. Rows in groups of 4:
// each thread computes 4 partial dots -> LDS; wave w reduces row w (6 shfl in
// ONE wave); 2 barriers per 4 rows; defer-max softmax (rescale only when the
// group max exceeds m+8; block-uniform branch).
template <int NCH>
__global__ __launch_bounds__(256, 4) void fused_pass(const float* __restrict__ q,
                                                     const float* __restrict__ enc,
                                                     float* __restrict__ energy,
                                                     float* __restrict__ partial,
                                                     float* __restrict__ ml) {
    constexpr int CHS = SS / NCH;   // rows per block
    constexpr int NR  = CHS / 4;    // 4-row rounds
    int blk = blockIdx.x;           // b*NCH + cb
    int b   = blk / NCH;
    int cb  = blk % NCH;
    int tid = threadIdx.x;
    int wid = tid >> 6;
    int ln  = tid & 63;

    __shared__ float pdl[4][256];   // per-row partial dots
    __shared__ float ew[4];         // reduced energies

    float4 qv = ((const float4*)(q + (size_t)b * DD))[tid];

    int s0 = cb * CHS;
    const float4* base = (const float4*)enc;
    const size_t rs = (size_t)BB * (DD / 4);            // float4 per s step
    size_t idx = (size_t)(s0 * BB + b) * (DD / 4) + tid;

    float m = -1e30f, l = 0.f;
    float4 acc = {0.f, 0.f, 0.f, 0.f};
    float4 vc[4], vn[4];

#pragma unroll
    for (int j = 0; j < 4; ++j) vc[j] = base[idx + (size_t)j * rs];

#pragma unroll 2
    for (int r = 0; r < NR; ++r) {
        if (r + 1 < NR) {
#pragma unroll
            for (int j = 0; j < 4; ++j)
                vn[j] = base[idx + (size_t)((r + 1) * 4 + j) * rs];
        }

        float pd[4];
#pragma unroll
        for (int j = 0; j < 4; ++j) {
            float4 v = vc[j];
            pd[j] = v.x * qv.x + v.y * qv.y + v.z * qv.z + v.w * qv.w;
        }
#pragma unroll
        for (int j = 0; j < 4; ++j) pdl[j][tid] = pd[j];
        __syncthreads();

        // wave wid reduces row wid only
        {
            float4 t = ((const float4*)pdl[wid])[ln];
            float s = t.x + t.y + t.z + t.w;
#pragma unroll
            for (int off = 32; off > 0; off >>= 1)
                s += __shfl_xor(s, off, 64);
            if (ln == 0) {
                ew[wid] = s;
                energy[b * SS + s0 + r * 4 + wid] = s;
            }
        }
        __syncthreads();

        float e0 = ew[0], e1 = ew[1], e2 = ew[2], e3 = ew[3];
        float pmax = fmaxf(fmaxf(e0, e1), fmaxf(e2, e3));
        if (pmax > m + 8.f) {              // block-uniform (same LDS values)
            float sc = __expf(m - pmax);
            l *= sc;
            acc.x *= sc; acc.y *= sc; acc.z *= sc; acc.w *= sc;
            m = pmax;
        }
        float p0 = __expf(e0 - m), p1 = __expf(e1 - m);
        float p2 = __expf(e2 - m), p3 = __expf(e3 - m);
        l += p0 + p1 + p2 + p3;
        acc.x += p0 * vc[0].x + p1 * vc[1].x + p2 * vc[2].x + p3 * vc[3].x;
        acc.y += p0 * vc[0].y + p1 * vc[1].y + p2 * vc[2].y + p3 * vc[3].y;
        acc.z += p0 * vc[0].z + p1 * vc[1].z + p2 * vc[2].z + p3 * vc[3].z;
        acc.w += p0 * vc[0].w + p1 * vc[1].w + p2 * vc[2].w + p3 * vc[3].w;

#pragma unroll
        for (int j = 0; j < 4; ++j) vc[j] = vn[j];
    }

    ((float4*)(partial + (size_t)blk * DD))[tid] = acc;
    if (tid == 0) { ml[blk * 2] = m; ml[blk * 2 + 1] = l; }
}

// K2: merge nch chunk partials per b -> values; write scores.
// Grid = BB*8: block owns D/8 of values and S/8 of scores.
__global__ __launch_bounds__(256) void merge_scores(const float* __restrict__ partial,
                                                    const float* __restrict__ ml,
                                                    const float* __restrict__ energy,
                                                    float* __restrict__ values,
                                                    float* __restrict__ scores,
                                                    int nch) {
    int blk = blockIdx.x;
    int b   = blk >> 3;
    int oct = blk & 7;
    int tid = threadIdx.x;
    __shared__ float sm[64], sl[64], sw[64];

    if (tid < nch) {
        sm[tid] = ml[(b * nch + tid) * 2];
        sl[tid] = ml[(b * nch + tid) * 2 + 1];
    }
    __syncthreads();

    float M = -1e30f;
    for (int c = 0; c < nch; ++c) M = fmaxf(M, sm[c]);
    if (tid < nch) sw[tid] = __expf(sm[tid] - M);
    __syncthreads();

    float L = 0.f;
    for (int c = 0; c < nch; ++c) L += sw[c] * sl[c];
    float inv = 1.f / L;

    if (tid < 128) {
        int d = oct * 128 + tid;
        float acc = 0.f;
        for (int c = 0; c < nch; ++c)
            acc += sw[c] * partial[(size_t)(b * nch + c) * DD + d];
        values[b * DD + d] = acc * inv;
    }

    int sidx = b * SS + oct * 256 + tid;
    scores[sidx] = __expf(energy[sidx] - M) * inv;
}

extern "C" void kernel_launch(void* const* d_in, const int* in_sizes, int n_in,
                              void* d_out, int out_size, void* d_ws, size_t ws_size,
                              hipStream_t stream) {
    const float* q   = (const float*)d_in[0];   // (1,B,D)
    const float* enc = (const float*)d_in[1];   // (S,B,D)
    float* out    = (float*)d_out;
    float* values = out;                        // (B,D)
    float* scores = out + BB * DD;              // (B,S)

    size_t need64 = ((size_t)BB * SS + (size_t)BB * 64 * DD + (size_t)BB * 64 * 2)
                    * sizeof(float);
    int nch = (ws_size >= need64) ? 64 : 32;

    float* energy  = (float*)d_ws;                         // BB*SS
    float* partial = energy + BB * SS;                     // BB*nch*DD
    float* ml      = partial + (size_t)BB * nch * DD;      // BB*nch*2

    if (nch == 64)
        fused_pass<64><<<BB * 64, 256, 0, stream>>>(q, enc, energy, partial, ml);
    else
        fused_pass<32><<<BB * 32, 256, 0, stream>>>(q, enc, energy, partial, ml);
    merge_scores<<<BB * 8, 256, 0, stream>>>(partial, ml, energy, values, scores, nch);
}